// Round 1
// baseline (2163.469 us; speedup 1.0000x reference)
//
#include <hip/hip_runtime.h>
#include <stdint.h>

#define M_DIM 8192
#define N_DIM 16384
#define K_DIM 4096

typedef __attribute__((ext_vector_type(4))) float f32x4;
typedef __attribute__((ext_vector_type(8))) __bf16 bf16x8;
typedef __attribute__((ext_vector_type(8))) unsigned short u16x8;
typedef __attribute__((ext_vector_type(4))) int i32x4;

// fp32 -> bf16 bits, round-to-nearest-even (inputs are finite; no NaN path needed)
__device__ __forceinline__ unsigned short f32_bf16(float f) {
  union { float f; unsigned int u; } v; v.f = f;
  unsigned int r = v.u + (0x7FFFu + ((v.u >> 16) & 1u));
  return (unsigned short)(r >> 16);
}

__global__ __launch_bounds__(256) void cvt_x_kernel(const float* __restrict__ in,
                                                    unsigned short* __restrict__ out,
                                                    int n8) {
  int i = blockIdx.x * 256 + threadIdx.x;
  if (i >= n8) return;
  size_t b = (size_t)i * 8;
  f32x4 a0 = *(const f32x4*)(in + b);
  f32x4 a1 = *(const f32x4*)(in + b + 4);
  u16x8 o;
  o[0] = f32_bf16(a0[0]); o[1] = f32_bf16(a0[1]);
  o[2] = f32_bf16(a0[2]); o[3] = f32_bf16(a0[3]);
  o[4] = f32_bf16(a1[0]); o[5] = f32_bf16(a1[1]);
  o[6] = f32_bf16(a1[2]); o[7] = f32_bf16(a1[3]);
  *(u16x8*)(out + b) = o;
}

// int32 (values in [-128,127]) -> bf16 bits; integers <= 128 are EXACT in bf16.
__global__ __launch_bounds__(256) void cvt_w_kernel(const int* __restrict__ in,
                                                    unsigned short* __restrict__ out,
                                                    int n8) {
  int i = blockIdx.x * 256 + threadIdx.x;
  if (i >= n8) return;
  size_t b = (size_t)i * 8;
  i32x4 a0 = *(const i32x4*)(in + b);
  i32x4 a1 = *(const i32x4*)(in + b + 4);
  u16x8 o;
  o[0] = f32_bf16((float)a0[0]); o[1] = f32_bf16((float)a0[1]);
  o[2] = f32_bf16((float)a0[2]); o[3] = f32_bf16((float)a0[3]);
  o[4] = f32_bf16((float)a1[0]); o[5] = f32_bf16((float)a1[1]);
  o[6] = f32_bf16((float)a1[2]); o[7] = f32_bf16((float)a1[3]);
  *(u16x8*)(out + b) = o;
}

// async global->LDS, 16B per lane; LDS dest = wave-uniform base + lane*16
__device__ __forceinline__ void async_copy16(const void* g, void* l) {
  __builtin_amdgcn_global_load_lds(
      (__attribute__((address_space(1))) void*)(uintptr_t)g,
      (__attribute__((address_space(3))) void*)l,
      16, 0, 0);
}

// C[m][n] = sum_k A[m][k] * W[n][k]; epilogue: * scale[n] + bias[n]
// 128x128 tile, BK=32, 4 waves each computing 64x64 via 4x4 MFMA 16x16x32 bf16.
__global__ __launch_bounds__(256, 2) void gemm_kernel(
    const unsigned short* __restrict__ A,   // [M,K] bf16 bits
    const unsigned short* __restrict__ Wb,  // [N,K] bf16 bits (integer weight values)
    const float* __restrict__ scale,
    const float* __restrict__ bias,
    float* __restrict__ out) {
  __shared__ unsigned short Alds[128 * 32];
  __shared__ unsigned short Blds[128 * 32];

  const int tid = threadIdx.x;
  const int wave = tid >> 6;
  const int lane = tid & 63;

  const int n0 = blockIdx.x * 128;
  const int m0 = blockIdx.y * 128;
  const int wm = (wave >> 1) * 64;  // wave's M offset within tile
  const int wn = (wave & 1) * 64;   // wave's N offset within tile

  f32x4 acc[4][4];
#pragma unroll
  for (int i = 0; i < 4; ++i)
#pragma unroll
    for (int j = 0; j < 4; ++j) acc[i][j] = (f32x4){0.f, 0.f, 0.f, 0.f};

  // Staging: each tile (128 rows x 32 cols bf16 = 8 KB) = 8 chunks of 1 KB.
  // Wave w loads chunks {w, w+4} of A and of B.
  // Chunk c, lane i: LDS byte c*1024 + i*16  ->  row c*16 + (i>>2), col (i&3)*8.
  const int c0 = wave, c1 = wave + 4;
  const int r0 = c0 * 16 + (lane >> 2);
  const int r1 = c1 * 16 + (lane >> 2);
  const int sc = (lane & 3) * 8;

  const unsigned short* Ag0 = A + (size_t)(m0 + r0) * K_DIM + sc;
  const unsigned short* Ag1 = A + (size_t)(m0 + r1) * K_DIM + sc;
  const unsigned short* Bg0 = Wb + (size_t)(n0 + r0) * K_DIM + sc;
  const unsigned short* Bg1 = Wb + (size_t)(n0 + r1) * K_DIM + sc;

  unsigned short* Al0 = &Alds[c0 * 512];
  unsigned short* Al1 = &Alds[c1 * 512];
  unsigned short* Bl0 = &Blds[c0 * 512];
  unsigned short* Bl1 = &Blds[c1 * 512];

  // Fragment addressing (verified m89/m91): operand [row=lane&15][k=(lane>>4)*8 + j]
  const int frow = lane & 15;
  const int fk = (lane >> 4) * 8;

  for (int kt = 0; kt < K_DIM; kt += 32) {
    async_copy16(Ag0 + kt, Al0);
    async_copy16(Ag1 + kt, Al1);
    async_copy16(Bg0 + kt, Bl0);
    async_copy16(Bg1 + kt, Bl1);
    __syncthreads();  // compiler drains vmcnt(0) before s_barrier

    bf16x8 af[4], bfv[4];
#pragma unroll
    for (int i = 0; i < 4; ++i)
      af[i] = *(const bf16x8*)&Alds[(wm + i * 16 + frow) * 32 + fk];
#pragma unroll
    for (int j = 0; j < 4; ++j)
      bfv[j] = *(const bf16x8*)&Blds[(wn + j * 16 + frow) * 32 + fk];

#pragma unroll
    for (int i = 0; i < 4; ++i)
#pragma unroll
      for (int j = 0; j < 4; ++j)
        acc[i][j] = __builtin_amdgcn_mfma_f32_16x16x32_bf16(af[i], bfv[j], acc[i][j], 0, 0, 0);

    __syncthreads();  // all waves done reading LDS before next stage
  }

  // Epilogue. C/D layout: col = lane&15, row = (lane>>4)*4 + reg (m89-verified).
#pragma unroll
  for (int j = 0; j < 4; ++j) {
    const int col = n0 + wn + j * 16 + (lane & 15);
    const float s = scale[col];
    const float bb = bias[col];
#pragma unroll
    for (int i = 0; i < 4; ++i) {
      const int row = m0 + wm + i * 16 + (lane >> 4) * 4;
      float* o = out + (size_t)row * N_DIM + col;
#pragma unroll
      for (int r = 0; r < 4; ++r)
        o[(size_t)r * N_DIM] = acc[i][j][r] * s + bb;
    }
  }
}

// Correctness fallback if workspace is too small (not expected to trigger).
__global__ __launch_bounds__(256) void gemm_fallback(
    const float* __restrict__ X, const int* __restrict__ W,
    const float* __restrict__ scale, const float* __restrict__ bias,
    float* __restrict__ out) {
  __shared__ float Xs[64][17];
  __shared__ float Ws[64][17];
  const int tx = threadIdx.x & 15, ty = threadIdx.x >> 4;
  const int m0 = blockIdx.y * 64, n0 = blockIdx.x * 64;
  float acc[4][4] = {};
  for (int k0 = 0; k0 < K_DIM; k0 += 16) {
    for (int t = threadIdx.x; t < 64 * 16; t += 256) {
      int r = t >> 4, c = t & 15;
      Xs[r][c] = X[(size_t)(m0 + r) * K_DIM + k0 + c];
      Ws[r][c] = (float)W[(size_t)(n0 + r) * K_DIM + k0 + c];
    }
    __syncthreads();
#pragma unroll
    for (int kk = 0; kk < 16; ++kk)
#pragma unroll
      for (int i = 0; i < 4; ++i)
#pragma unroll
        for (int j = 0; j < 4; ++j)
          acc[i][j] += Xs[ty * 4 + i][kk] * Ws[tx * 4 + j][kk];
    __syncthreads();
  }
  for (int i = 0; i < 4; ++i)
    for (int j = 0; j < 4; ++j) {
      int row = m0 + ty * 4 + i, col = n0 + tx * 4 + j;
      out[(size_t)row * N_DIM + col] = acc[i][j] * scale[col] + bias[col];
    }
}

extern "C" void kernel_launch(void* const* d_in, const int* in_sizes, int n_in,
                              void* d_out, int out_size, void* d_ws, size_t ws_size,
                              hipStream_t stream) {
  const float* x = (const float*)d_in[0];
  const int* w8 = (const int*)d_in[1];      // integer inputs arrive as int32
  const float* scale = (const float*)d_in[2];
  const float* bias = (const float*)d_in[3];
  float* out = (float*)d_out;

  const size_t a_elems = (size_t)M_DIM * K_DIM;
  const size_t w_elems = (size_t)N_DIM * K_DIM;
  const size_t need = (a_elems + w_elems) * sizeof(unsigned short);

  if (ws_size >= need) {
    unsigned short* A = (unsigned short*)d_ws;
    unsigned short* Wb = A + a_elems;
    int nx8 = (int)(a_elems / 8);
    int nw8 = (int)(w_elems / 8);
    cvt_x_kernel<<<(nx8 + 255) / 256, 256, 0, stream>>>(x, A, nx8);
    cvt_w_kernel<<<(nw8 + 255) / 256, 256, 0, stream>>>(w8, Wb, nw8);
    dim3 grid(N_DIM / 128, M_DIM / 128);
    gemm_kernel<<<grid, 256, 0, stream>>>(A, Wb, scale, bias, out);
  } else {
    dim3 grid(N_DIM / 64, M_DIM / 64);
    gemm_fallback<<<grid, 256, 0, stream>>>(x, w8, scale, bias, out);
  }
}

// Round 2
// 1358.435 us; speedup vs baseline: 1.5926x; 1.5926x over previous
//
#include <hip/hip_runtime.h>
#include <stdint.h>

#define M_DIM 8192
#define N_DIM 16384
#define K_DIM 4096

typedef __attribute__((ext_vector_type(4))) float f32x4;
typedef __attribute__((ext_vector_type(4))) int i32x4;

// ---------------------------------------------------------------------------
// quant_x: per-row dynamic int8 quantization of x.
// One block per row (8192 rows, K=4096). Each thread holds 16 elems in regs,
// block-reduces absmax, then quantizes+packs 4 bytes/dword, 4 dwords/thread.
// ---------------------------------------------------------------------------
__global__ __launch_bounds__(256) void quant_x_kernel(const float* __restrict__ x,
                                                      int* __restrict__ xq,
                                                      float* __restrict__ sx) {
  const int row = blockIdx.x;
  const int t = threadIdx.x;
  const float* xr = x + (size_t)row * K_DIM;
  f32x4 v[4];
#pragma unroll
  for (int c = 0; c < 4; ++c) v[c] = *(const f32x4*)(xr + c * 1024 + t * 4);
  float amax = 0.f;
#pragma unroll
  for (int c = 0; c < 4; ++c)
#pragma unroll
    for (int e = 0; e < 4; ++e) amax = fmaxf(amax, fabsf(v[c][e]));
#pragma unroll
  for (int off = 32; off > 0; off >>= 1)
    amax = fmaxf(amax, __shfl_xor(amax, off, 64));
  __shared__ float wmax[4];
  if ((t & 63) == 0) wmax[t >> 6] = amax;
  __syncthreads();
  amax = fmaxf(fmaxf(wmax[0], wmax[1]), fmaxf(wmax[2], wmax[3]));
  const float inv = amax > 0.f ? 127.f / amax : 0.f;
  if (t == 0) sx[row] = amax * (1.f / 127.f);
  int* xqr = xq + (size_t)row * (K_DIM / 4);
#pragma unroll
  for (int c = 0; c < 4; ++c) {
    int b0 = (int)rintf(v[c][0] * inv) & 255;
    int b1 = (int)rintf(v[c][1] * inv) & 255;
    int b2 = (int)rintf(v[c][2] * inv) & 255;
    int b3 = (int)rintf(v[c][3] * inv) & 255;
    xqr[c * 256 + t] = b0 | (b1 << 8) | (b2 << 16) | (b3 << 24);
  }
}

// ---------------------------------------------------------------------------
// cvt_w8: int32 weights (values in [-128,127]) -> packed int8.
// 16 ints -> 4 dwords per thread.
// ---------------------------------------------------------------------------
__global__ __launch_bounds__(256) void cvt_w8_kernel(const int* __restrict__ in,
                                                     int* __restrict__ outp,
                                                     int n16) {
  int i = blockIdx.x * 256 + threadIdx.x;
  if (i >= n16) return;
  size_t b = (size_t)i * 16;
  i32x4 o;
#pragma unroll
  for (int c = 0; c < 4; ++c) {
    i32x4 a = *(const i32x4*)(in + b + c * 4);
    o[c] = (a[0] & 255) | ((a[1] & 255) << 8) | ((a[2] & 255) << 16) | ((a[3] & 255) << 24);
  }
  *(i32x4*)(outp + (size_t)i * 4) = o;
}

// async global->LDS, 16B per lane; LDS dest = wave-uniform base + lane*16
__device__ __forceinline__ void async_copy16(const void* g, void* l) {
  __builtin_amdgcn_global_load_lds(
      (__attribute__((address_space(1))) void*)(uintptr_t)g,
      (__attribute__((address_space(3))) void*)l,
      16, 0, 0);
}

// ---------------------------------------------------------------------------
// int8 GEMM: C[m][n] = sum_k xq[m][k]*wq[n][k]; out = C * sx[m]*scale[n] + bias[n]
// 128x128 tile, BK=64 (int8), 4 waves x (4x4 of mfma_i32_16x16x64_i8).
// XOR bank swizzle: k-chunk g of row r lives at LDS slot g ^ ((r>>1)&3)
// (16B slots, 4 per row) -> fragment reads are 2-way-aliased = conflict-free.
// Grid: 1D, mi = bid&63 fastest -> A (32MB) LLC-resident; XCD=bid%8 pins the
// same 8 A-tiles (4MB = one XCD L2) per XCD.
// ---------------------------------------------------------------------------
__global__ __launch_bounds__(256, 4) void gemm_i8_kernel(
    const signed char* __restrict__ A,   // [M,K] int8
    const signed char* __restrict__ Wq,  // [N,K] int8
    const float* __restrict__ sx,        // [M]
    const float* __restrict__ scale,     // [N]
    const float* __restrict__ bias,      // [N]
    float* __restrict__ out) {
  __shared__ __attribute__((aligned(16))) signed char Alds[128 * 64];
  __shared__ __attribute__((aligned(16))) signed char Blds[128 * 64];

  const int tid = threadIdx.x;
  const int wave = tid >> 6;
  const int lane = tid & 63;

  const int mi = blockIdx.x & 63;
  const int ni = blockIdx.x >> 6;
  const int m0 = mi * 128;
  const int n0 = ni * 128;
  const int wm = (wave >> 1) * 64;
  const int wn = (wave & 1) * 64;

  i32x4 acc[4][4];
#pragma unroll
  for (int i = 0; i < 4; ++i)
#pragma unroll
    for (int j = 0; j < 4; ++j) acc[i][j] = (i32x4){0, 0, 0, 0};

  // Staging: tile = 128 rows x 64 B = 8 KB = 8 chunks of 1 KB (16 rows each).
  // Wave w loads chunks {w, w+4}. Chunk c, lane i -> LDS byte c*1024 + i*16,
  // i.e. row rr = c*16 + (i>>2), slot (i&3). Global source k-chunk is
  // (i&3) ^ ((rr>>1)&3)  (XOR bank swizzle).
  const int c0 = wave, c1 = wave + 4;
  const int rr0 = c0 * 16 + (lane >> 2);
  const int rr1 = c1 * 16 + (lane >> 2);
  const int g0 = ((lane & 3) ^ ((rr0 >> 1) & 3)) * 16;
  const int g1 = ((lane & 3) ^ ((rr1 >> 1) & 3)) * 16;

  const signed char* Ag0 = A + (size_t)(m0 + rr0) * K_DIM + g0;
  const signed char* Ag1 = A + (size_t)(m0 + rr1) * K_DIM + g1;
  const signed char* Bg0 = Wq + (size_t)(n0 + rr0) * K_DIM + g0;
  const signed char* Bg1 = Wq + (size_t)(n0 + rr1) * K_DIM + g1;

  signed char* Al0 = &Alds[c0 * 1024];
  signed char* Al1 = &Alds[c1 * 1024];
  signed char* Bl0 = &Blds[c0 * 1024];
  signed char* Bl1 = &Blds[c1 * 1024];

  // Fragment: lane holds row frow = lane&15, k-bytes q*16..q*16+15, q=lane>>4.
  // Stored slot for k-chunk q of row frow is q ^ ((frow>>1)&3).
  const int frow = lane & 15;
  const int fb = ((lane >> 4) ^ ((frow >> 1) & 3)) * 16;

  for (int kt = 0; kt < K_DIM; kt += 64) {
    async_copy16(Ag0 + kt, Al0);
    async_copy16(Ag1 + kt, Al1);
    async_copy16(Bg0 + kt, Bl0);
    async_copy16(Bg1 + kt, Bl1);
    __syncthreads();

    i32x4 af[4], bfv[4];
#pragma unroll
    for (int i = 0; i < 4; ++i)
      af[i] = *(const i32x4*)&Alds[(wm + i * 16 + frow) * 64 + fb];
#pragma unroll
    for (int j = 0; j < 4; ++j)
      bfv[j] = *(const i32x4*)&Blds[(wn + j * 16 + frow) * 64 + fb];

#pragma unroll
    for (int i = 0; i < 4; ++i)
#pragma unroll
      for (int j = 0; j < 4; ++j)
        acc[i][j] = __builtin_amdgcn_mfma_i32_16x16x64_i8(af[i], bfv[j], acc[i][j], 0, 0, 0);

    __syncthreads();
  }

  // Epilogue. C/D layout (dtype-independent, m89/m101): col=lane&15,
  // row=(lane>>4)*4+reg.
  int colv[4];
  float sc[4], bi[4];
#pragma unroll
  for (int j = 0; j < 4; ++j) {
    colv[j] = n0 + wn + j * 16 + (lane & 15);
    sc[j] = scale[colv[j]];
    bi[j] = bias[colv[j]];
  }
#pragma unroll
  for (int i = 0; i < 4; ++i) {
    const int rowb = m0 + wm + i * 16 + (lane >> 4) * 4;
    float sxv[4];
#pragma unroll
    for (int r = 0; r < 4; ++r) sxv[r] = sx[rowb + r];
#pragma unroll
    for (int j = 0; j < 4; ++j)
#pragma unroll
      for (int r = 0; r < 4; ++r)
        out[(size_t)(rowb + r) * N_DIM + colv[j]] =
            (float)acc[i][j][r] * sxv[r] * sc[j] + bi[j];
  }
}

// Correctness fallback if workspace is too small (not expected to trigger).
__global__ __launch_bounds__(256) void gemm_fallback(
    const float* __restrict__ X, const int* __restrict__ W,
    const float* __restrict__ scale, const float* __restrict__ bias,
    float* __restrict__ out) {
  __shared__ float Xs[64][17];
  __shared__ float Ws[64][17];
  const int tx = threadIdx.x & 15, ty = threadIdx.x >> 4;
  const int m0 = blockIdx.y * 64, n0 = blockIdx.x * 64;
  float acc[4][4] = {};
  for (int k0 = 0; k0 < K_DIM; k0 += 16) {
    for (int t = threadIdx.x; t < 64 * 16; t += 256) {
      int r = t >> 4, c = t & 15;
      Xs[r][c] = X[(size_t)(m0 + r) * K_DIM + k0 + c];
      Ws[r][c] = (float)W[(size_t)(n0 + r) * K_DIM + k0 + c];
    }
    __syncthreads();
#pragma unroll
    for (int kk = 0; kk < 16; ++kk)
#pragma unroll
      for (int i = 0; i < 4; ++i)
#pragma unroll
        for (int j = 0; j < 4; ++j)
          acc[i][j] += Xs[ty * 4 + i][kk] * Ws[tx * 4 + j][kk];
    __syncthreads();
  }
  for (int i = 0; i < 4; ++i)
    for (int j = 0; j < 4; ++j) {
      int row = m0 + ty * 4 + i, col = n0 + tx * 4 + j;
      out[(size_t)row * N_DIM + col] = acc[i][j] * scale[col] + bias[col];
    }
}

extern "C" void kernel_launch(void* const* d_in, const int* in_sizes, int n_in,
                              void* d_out, int out_size, void* d_ws, size_t ws_size,
                              hipStream_t stream) {
  const float* x = (const float*)d_in[0];
  const int* w8 = (const int*)d_in[1];  // integer inputs arrive as int32
  const float* scale = (const float*)d_in[2];
  const float* bias = (const float*)d_in[3];
  float* out = (float*)d_out;

  const size_t xq_bytes = (size_t)M_DIM * K_DIM;           // int8
  const size_t wq_bytes = (size_t)N_DIM * K_DIM;           // int8
  const size_t sx_bytes = (size_t)M_DIM * sizeof(float);
  const size_t need = xq_bytes + wq_bytes + sx_bytes;

  if (ws_size >= need) {
    signed char* xq = (signed char*)d_ws;
    signed char* wq = xq + xq_bytes;
    float* sx = (float*)(wq + wq_bytes);

    quant_x_kernel<<<M_DIM, 256, 0, stream>>>(x, (int*)xq, sx);
    int nw16 = (int)(wq_bytes / 16);
    cvt_w8_kernel<<<(nw16 + 255) / 256, 256, 0, stream>>>(w8, (int*)wq, nw16);
    gemm_i8_kernel<<<(M_DIM / 128) * (N_DIM / 128), 256, 0, stream>>>(
        xq, wq, sx, scale, bias, out);
  } else {
    dim3 grid(N_DIM / 64, M_DIM / 64);
    gemm_fallback<<<grid, 256, 0, stream>>>(x, w8, scale, bias, out);
  }
}